// Round 1
// 144.182 us; speedup vs baseline: 1.2205x; 1.2205x over previous
//
#include <hip/hip_runtime.h>
#include <math.h>

#define IMG   512
#define NFILT 32
#define PI_F  3.14159265358979323846f
#define GS    104      // LDS row stride in halves (208 B): b128 across lanes = 2-way banks (free)

typedef _Float16 v8h __attribute__((ext_vector_type(8)));
typedef float    v4f __attribute__((ext_vector_type(4)));

__device__ __forceinline__ unsigned pkrtz(float a, float b) {
    typedef __fp16 f16x2 __attribute__((ext_vector_type(2)));
    union { f16x2 h; unsigned u; } x;
    x.h = __builtin_amdgcn_cvt_pkrtz(a, b);
    return x.u;
}

template <int CTRL>
__device__ __forceinline__ float dpp_add(float v) {
    int t = __builtin_amdgcn_update_dpp(0, __float_as_int(v), CTRL, 0xf, 0xf, true);
    return v + __int_as_float(t);
}

#if __has_builtin(__builtin_amdgcn_sqrtf)
__device__ __forceinline__ float fsqrt(float x) { return __builtin_amdgcn_sqrtf(x); }
#else
__device__ __forceinline__ float fsqrt(float x) { return sqrtf(x); }
#endif

__device__ __forceinline__ v8h ldfrag(const uint4* p) {
    union { uint4 u; v8h h; } x; x.u = *p; return x.h;
}

__device__ __forceinline__ v8h neg8h(v8h a) {           // flip f16 sign bits
    union { v8h h; uint4 u; } x; x.h = a;
    x.u.x ^= 0x80008000u; x.u.y ^= 0x80008000u;
    x.u.z ^= 0x80008000u; x.u.w ^= 0x80008000u;
    return x.h;
}

// ---------------------------------------------------------------------------
// tabs layout (dwords): [filter:32][table:5][copy:8][block:20][dw:4]
//   tables: 0 g_re, 1 g_im, 2 f_re, 3 f_im, 4 -f_im (tbl4 kept for layout)
//   copy c, block i holds halves tap(8*i-64+c .. +7); tap(t)=0 unless 0<=t<32.
// One block per filter: compute 160 base taps into LDS once, expand by gather.
// ---------------------------------------------------------------------------
__global__ void make_tables(unsigned* __restrict__ tabs) {
    __shared__ _Float16 P[5][168];      // P[tbl][p] = tap(p-64), zero-padded
    const int fo = blockIdx.x;
    const int tid = threadIdx.x;
    for (int e = tid; e < 5 * 168; e += 256) ((_Float16*)P)[e] = (_Float16)0.0f;
    __syncthreads();
    if (tid < 160) {
        int tbl = tid >> 5, t = tid & 31;
        int s = (fo >> 3) + 1, o = fo & 7;
        float theta = (float)o * (PI_F / 7.0f);      // linspace(0, pi, 8)
        float sf = (float)s * 2.0f;                  // scale * SIGMA
        float kf = 2.0f * PI_F / ((float)s * sf);
        float a = kf * cosf(theta), b = kf * sinf(theta);
        float d = (float)(t - 16);
        float env = expf(-0.5f * d * d / (sf * sf));
        float v;
        switch (tbl) {
            case 0: v =  env * cosf(b * d); break;
            case 1: v =  env * sinf(b * d); break;
            case 2: v =  env * cosf(a * d); break;
            case 3: v =  env * sinf(a * d); break;
            default: v = -env * sinf(a * d); break;
        }
        P[tbl][t + 64] = (_Float16)v;
    }
    __syncthreads();
    unsigned* dst = tabs + (size_t)fo * 3200;
    for (int e = tid; e < 3200; e += 256) {
        int tbl  = e / 640;  int rem2 = e - tbl * 640;
        int copy = rem2 / 80; int idw = rem2 - copy * 80;
        int p0 = (idw >> 2) * 8 + copy + (idw & 3) * 2;   // = t0 + 64
        union { unsigned u; _Float16 h[2]; } p;
        p.h[0] = P[tbl][p0];
        p.h[1] = P[tbl][p0 + 1];
        dst[e] = p.u;
    }
}

// ---------------------------------------------------------------------------
// Fused kernel: S0 pool + MFMA separable Gabor conv + |.| + pool -> S1.
// R14: merged fsplit (512 blocks = 8n x 64 tiles, each does ALL 32 filters)
//   -> gray staging + S0 done ONCE per tile (was 3x), FETCH ~83->~32 MB.
// Grid 512 = exactly 2 blocks/CU, so LDS budget doubles for free:
//   double-buffered T -> ONE barrier per filter (pass B(f) || pass A(f+1)),
//   and VGPR cap 128 (__launch_bounds__(512,4)) -> cross-filter register
//   prefetch of G/F table fragments (spilled at the old 84-VGPR cap).
// LDS 73.5 KB -> 2 blocks/CU, zero-tail single resident round.
// ---------------------------------------------------------------------------
__launch_bounds__(512, 4)
__global__ void conv_kernel(const float* __restrict__ x,
                            const uint4* __restrict__ tabs,
                            float* __restrict__ s0out,
                            float* __restrict__ s1out) {
    __shared__ _Float16 gray[96 * GS];       // 19968 B
    __shared__ _Float16 Tre[2][64 * GS];     // 2 x 13312 B  (T^T: [col c][row m])
    __shared__ _Float16 Tim[2][64 * GS];     // 2 x 13312 B
    __shared__ float    s1st[NFILT * 16];    // 2048 B, staged pooled outputs

    const int bx = blockIdx.x;
    const int n  = bx >> 6;                  // image
    const int t6 = bx & 63;                  // tile
    const int ty = t6 >> 3, tx = t6 & 7;
    const int r0g = ty * 64 - 16;
    const int c0g = tx * 64 - 16;            // 16-aligned -> float4-aligned
    const int tid = threadIdx.x;

    // ---- stage gray = 3-channel mean (f16), float4 loads, group bounds ----
    // tasks: 96 rows x 24 col-groups of 4; cols 96..103 of GS never read.
    {
        const float* c0p = x + (size_t)n * 3 * IMG * IMG;
        const float* c1p = c0p + IMG * IMG;
        const float* c2p = c0p + 2 * IMG * IMG;
        for (int e = tid; e < 96 * 24; e += 512) {
            int hr = e / 24, g4 = e - hr * 24;
            int hc0 = g4 * 4;
            int gr = r0g + hr, gc0 = c0g + hc0;
            float4 v = make_float4(0.f, 0.f, 0.f, 0.f);
            if (hr < 95 && (unsigned)gr < IMG && (unsigned)gc0 < IMG) {
                size_t off = ((size_t)gr * IMG + gc0) >> 2;
                float4 a = ((const float4*)c0p)[off];
                float4 b = ((const float4*)c1p)[off];
                float4 c = ((const float4*)c2p)[off];
                v.x = (a.x + b.x + c.x) * (1.0f / 3.0f);
                v.y = (a.y + b.y + c.y) * (1.0f / 3.0f);
                v.z = (a.z + b.z + c.z) * (1.0f / 3.0f);
                v.w = (hc0 == 92) ? 0.0f : (a.w + b.w + c.w) * (1.0f / 3.0f);
            }
            uint2 w2;
            w2.x = pkrtz(v.x, v.y);
            w2.y = pkrtz(v.z, v.w);
            *(uint2*)(&gray[hr * GS + hc0]) = w2;
        }
    }
    __syncthreads();

    // ---- fused S0: 16x16 avg-pool of gray interior (once per tile now) ----
    if (tid < 256) {
        int cell = tid >> 4, sub = tid & 15;
        int pr = cell >> 2, pc = cell & 3;
        const _Float16* row = &gray[(16 + pr * 16 + sub) * GS + 16 + pc * 16];
        float s = 0.0f;
        #pragma unroll
        for (int j = 0; j < 16; ++j) s += (float)row[j];
        s += __shfl_xor(s, 1);
        s += __shfl_xor(s, 2);
        s += __shfl_xor(s, 4);
        s += __shfl_xor(s, 8);
        if (sub == 0)
            s0out[(size_t)n * 1024 + (ty * 4 + pr) * 32 + (tx * 4 + pc)] = s * (1.0f / 256.0f);
    }

    const int lane = tid & 63;
    const int w    = tid >> 6;
    const int r4   = w & 3;                 // pass A N-tile / pass B M-tile
    const int half = w >> 2;                // splits mt (pass A) / nt (pass B)
    const int nn   = lane & 15;
    const int q8   = (lane >> 4) << 3;      // k-offset within K=32 fragment
    const int q4   = (lane >> 4) << 2;      // C/D row base within 16-tile
    const int cr   = r4 * 16 + nn;          // pass A: col c; pass B: row r
    const int u    = q8 - cr + 64;          // tap-phase for fragment tables
    const int b0   = r4 >> 1;               // first needed k-block (band skip)
    const int uoff = (u & 7) * 20 + (u >> 3);

    // ---- hoist filter-invariant gray A-fragments into registers ----
    v8h Agray[3][2];
    #pragma unroll
    for (int mi = 0; mi < 3; ++mi)
        #pragma unroll
        for (int j = 0; j < 2; ++j)
            Agray[mi][j] = *(const v8h*)(&gray[((half * 3 + mi) * 16 + nn) * GS + (b0 + j) * 32 + q8]);

    // ---- prologue: A(0) -> T[0]; F(0) loads issued before the barrier ----
    v8h Fre[2], Fim[2];
    {
        const uint4* fb0 = tabs + uoff;
        v8h Gre0[2], Gim0[2];
        #pragma unroll
        for (int j = 0; j < 2; ++j) {
            int idx = (b0 + j) * 4;
            Gre0[j] = ldfrag(fb0 + idx);
            Gim0[j] = ldfrag(fb0 + 160 + idx);
        }
        #pragma unroll
        for (int mi = 0; mi < 3; ++mi) {
            int mt = half * 3 + mi;
            v4f aR = {0.f, 0.f, 0.f, 0.f}, aI = {0.f, 0.f, 0.f, 0.f};
            #pragma unroll
            for (int j = 0; j < 2; ++j) {
                aR = __builtin_amdgcn_mfma_f32_16x16x32_f16(Agray[mi][j], Gre0[j], aR, 0, 0, 0);
                aI = __builtin_amdgcn_mfma_f32_16x16x32_f16(Agray[mi][j], Gim0[j], aI, 0, 0, 0);
            }
            int mb = mt * 16 + q4;
            uint2 pr, pi;
            pr.x = pkrtz(aR[0], aR[1]);  pr.y = pkrtz(aR[2], aR[3]);
            pi.x = pkrtz(aI[0], aI[1]);  pi.y = pkrtz(aI[2], aI[3]);
            *(uint2*)(&Tre[0][cr * GS + mb]) = pr;
            *(uint2*)(&Tim[0][cr * GS + mb]) = pi;
        }
        #pragma unroll
        for (int j = 0; j < 2; ++j) {
            int idx = (b0 + j) * 4;
            Fre[j] = ldfrag(fb0 + 320 + idx);
            Fim[j] = ldfrag(fb0 + 480 + idx);
        }
    }
    __syncthreads();

    // ---- main loop: one barrier per filter.  B(fo) reads T[fo&1] while
    // A(fo+1) writes T[(fo+1)&1]; F(fo+1)/G(fo+1) prefetched in registers. ----
    for (int fo = 0; fo < NFILT; ++fo) {
        const _Float16* Tr  = Tre[fo & 1];
        const _Float16* Ti  = Tim[fo & 1];
        _Float16*       Trn = Tre[(fo + 1) & 1];
        _Float16*       Tin = Tim[(fo + 1) & 1];
        const int  nxf  = (fo < NFILT - 1) ? fo + 1 : fo;   // clamp (wasted loads on last iter)
        const uint4* fbn = tabs + (size_t)nxf * 800 + uoff;

        // ---- G(fo+1) prefetch: issued early, consumed after B's 16 MFMAs ----
        v8h Gre[2], Gim[2];
        #pragma unroll
        for (int j = 0; j < 2; ++j) {
            int idx = (b0 + j) * 4;
            Gre[j] = ldfrag(fbn + idx);
            Gim[j] = ldfrag(fbn + 160 + idx);
        }

        v8h FiN[2];
        FiN[0] = neg8h(Fim[0]);
        FiN[1] = neg8h(Fim[1]);

        // ---- pass B: Out = F . T  (wave: M-tile r4, nt in half's range) ----
        #pragma unroll
        for (int ni = 0; ni < 2; ++ni) {
            int nt = half * 2 + ni;
            v4f cR = {0.f, 0.f, 0.f, 0.f}, cI = {0.f, 0.f, 0.f, 0.f};
            #pragma unroll
            for (int j = 0; j < 2; ++j) {
                v8h tR = *(const v8h*)(&Tr[(nt * 16 + nn) * GS + (b0 + j) * 32 + q8]);
                v8h tI = *(const v8h*)(&Ti[(nt * 16 + nn) * GS + (b0 + j) * 32 + q8]);
                cR = __builtin_amdgcn_mfma_f32_16x16x32_f16(Fre[j], tR, cR, 0, 0, 0);
                cR = __builtin_amdgcn_mfma_f32_16x16x32_f16(FiN[j], tI, cR, 0, 0, 0);
                cI = __builtin_amdgcn_mfma_f32_16x16x32_f16(Fre[j], tI, cI, 0, 0, 0);
                cI = __builtin_amdgcn_mfma_f32_16x16x32_f16(Fim[j], tR, cI, 0, 0, 0);
            }
            // magnitude + full 16x16-cell pool (cell = (r4, nt)); stage in LDS
            float m = 0.0f;
            #pragma unroll
            for (int r = 0; r < 4; ++r)
                m += fsqrt(fmaf(cR[r], cR[r], fmaf(cI[r], cI[r], 1e-8f)));
            m = dpp_add<0xB1>(m);   // quad_perm xor1
            m = dpp_add<0x4E>(m);   // quad_perm xor2
            m = dpp_add<0x141>(m);  // row_half_mirror
            m = dpp_add<0x140>(m);  // row_mirror
            m += __shfl_xor(m, 16);
            m += __shfl_xor(m, 32);
            if (lane == 0)
                s1st[fo * 16 + r4 * 4 + nt] = m;
        }

        // ---- pass A(fo+1): gray . G -> T[(fo+1)&1]; then F(fo+1) loads ----
        if (fo < NFILT - 1) {
            #pragma unroll
            for (int mi = 0; mi < 3; ++mi) {
                int mt = half * 3 + mi;
                v4f aR = {0.f, 0.f, 0.f, 0.f}, aI = {0.f, 0.f, 0.f, 0.f};
                #pragma unroll
                for (int j = 0; j < 2; ++j) {
                    aR = __builtin_amdgcn_mfma_f32_16x16x32_f16(Agray[mi][j], Gre[j], aR, 0, 0, 0);
                    aI = __builtin_amdgcn_mfma_f32_16x16x32_f16(Agray[mi][j], Gim[j], aI, 0, 0, 0);
                }
                // C/D: col=lane&15 -> c=cr, row=q4+reg -> m; write T^T[c][m] 4 halves
                int mb = mt * 16 + q4;
                uint2 pr, pi;
                pr.x = pkrtz(aR[0], aR[1]);  pr.y = pkrtz(aR[2], aR[3]);
                pi.x = pkrtz(aI[0], aI[1]);  pi.y = pkrtz(aI[2], aI[3]);
                *(uint2*)(&Trn[cr * GS + mb]) = pr;
                *(uint2*)(&Tin[cr * GS + mb]) = pi;
            }
            // F(fo+1) prefetch: latency spans the barrier into next iteration
            #pragma unroll
            for (int j = 0; j < 2; ++j) {
                int idx = (b0 + j) * 4;
                Fre[j] = ldfrag(fbn + 320 + idx);
                Fim[j] = ldfrag(fbn + 480 + idx);
            }
        }
        __syncthreads();        // T[(fo+1)&1] ready; T[fo&1] free for A(fo+2)
    }

    // ---- epilogue: flush staged S1 (loop ended with a barrier) ----
    float* s1b = s1out + (size_t)n * NFILT * 32 * 32;
    for (int e = tid; e < NFILT * 16; e += 512) {
        int fi = e >> 4, cell = e & 15;
        int r4c = cell >> 2, ntc = cell & 3;
        s1b[((size_t)fi * 32 + (ty * 4 + r4c)) * 32 + (tx * 4 + ntc)] =
            s1st[e] * (1.0f / 256.0f);
    }
}

// ---------------------------------------------------------------------------
extern "C" void kernel_launch(void* const* d_in, const int* in_sizes, int n_in,
                              void* d_out, int out_size, void* d_ws, size_t ws_size,
                              hipStream_t stream) {
    const float* x = (const float*)d_in[0];
    float* out = (float*)d_out;
    unsigned* tabs = (unsigned*)d_ws;          // 102400 dwords = 400 KB scratch

    hipLaunchKernelGGL(make_tables, dim3(32), dim3(256), 0, stream, tabs);
    hipLaunchKernelGGL(conv_kernel, dim3(512), dim3(512), 0, stream,
                       x, (const uint4*)tabs, out, out + 8192);
}

// Round 2
// 114.169 us; speedup vs baseline: 1.5414x; 1.2629x over previous
//
#include <hip/hip_runtime.h>
#include <math.h>

#define IMG   512
#define NFILT 32
#define NPAIR 16
#define PI_F  3.14159265358979323846f
#define GS    104      // LDS row stride in halves (208 B)

typedef _Float16 v8h __attribute__((ext_vector_type(8)));
typedef float    v4f __attribute__((ext_vector_type(4)));

__device__ __forceinline__ unsigned pkrtz(float a, float b) {
    typedef __fp16 f16x2 __attribute__((ext_vector_type(2)));
    union { f16x2 h; unsigned u; } x;
    x.h = __builtin_amdgcn_cvt_pkrtz(a, b);
    return x.u;
}

template <int CTRL>
__device__ __forceinline__ float dpp_add(float v) {
    int t = __builtin_amdgcn_update_dpp(0, __float_as_int(v), CTRL, 0xf, 0xf, true);
    return v + __int_as_float(t);
}

#if __has_builtin(__builtin_amdgcn_sqrtf)
__device__ __forceinline__ float fsqrt(float x) { return __builtin_amdgcn_sqrtf(x); }
#else
__device__ __forceinline__ float fsqrt(float x) { return sqrtf(x); }
#endif

__device__ __forceinline__ v8h ldfrag(const uint4* p) {
    union { uint4 u; v8h h; } x; x.u = *p; return x.h;
}

// ---------------------------------------------------------------------------
// tabs layout (dwords): [filter:32][table:5][copy:8][block:20][dw:4]
//   tables: 0 g_re, 1 g_im, 2 f_re, 3 f_im, 4 -f_im (tbl4 kept for layout)
//   copy c, block i holds halves tap(8*i-64+c .. +7); tap(t)=0 unless 0<=t<32.
// One block per filter: compute 160 base taps into LDS once, expand by gather.
// (With conjugate pairing, only filters o=0..3 of each scale are read by the
//  conv kernel; the rest are generated anyway — this kernel is ~2 us.)
// ---------------------------------------------------------------------------
__global__ void make_tables(unsigned* __restrict__ tabs) {
    __shared__ _Float16 P[5][168];      // P[tbl][p] = tap(p-64), zero-padded
    const int fo = blockIdx.x;
    const int tid = threadIdx.x;
    for (int e = tid; e < 5 * 168; e += 256) ((_Float16*)P)[e] = (_Float16)0.0f;
    __syncthreads();
    if (tid < 160) {
        int tbl = tid >> 5, t = tid & 31;
        int s = (fo >> 3) + 1, o = fo & 7;
        float theta = (float)o * (PI_F / 7.0f);      // linspace(0, pi, 8)
        float sf = (float)s * 2.0f;                  // scale * SIGMA
        float kf = 2.0f * PI_F / ((float)s * sf);
        float a = kf * cosf(theta), b = kf * sinf(theta);
        float d = (float)(t - 16);
        float env = expf(-0.5f * d * d / (sf * sf));
        float v;
        switch (tbl) {
            case 0: v =  env * cosf(b * d); break;
            case 1: v =  env * sinf(b * d); break;
            case 2: v =  env * cosf(a * d); break;
            case 3: v =  env * sinf(a * d); break;
            default: v = -env * sinf(a * d); break;
        }
        P[tbl][t + 64] = (_Float16)v;
    }
    __syncthreads();
    unsigned* dst = tabs + (size_t)fo * 3200;
    for (int e = tid; e < 3200; e += 256) {
        int tbl  = e / 640;  int rem2 = e - tbl * 640;
        int copy = rem2 / 80; int idw = rem2 - copy * 80;
        int p0 = (idw >> 2) * 8 + copy + (idw & 3) * 2;   // = t0 + 64
        union { unsigned u; _Float16 h[2]; } p;
        p.h[0] = P[tbl][p0];
        p.h[1] = P[tbl][p0 + 1];
        dst[e] = p.u;
    }
}

// ---------------------------------------------------------------------------
// Fused kernel: S0 pool + MFMA separable Gabor conv + |.| + pool -> S1.
// R15: conjugate-pair factoring.  theta and pi-theta share the column factor
// g (sin equal) and have conjugate row factors f (cos negated).  So:
//   - pass A (T = gray.g) is computed ONCE per pair -> A-MFMAs/T-writes halve
//   - pass B accumulates P1=Fre.Tre, P2=Fim.Tim, P3=Fre.Tim, P4=Fim.Tre;
//     out(o)   = (P1-P2, P3+P4),  out(7-o) = (P1+P2, P3-P4)
//     -> 4 MFMA chains yield BOTH filters: B-MFMAs halve as well.
// Loop: 16 pair-iterations, one barrier each (was 32).  Total MFMA work
// halves: 896 -> 448 per wave.  512 blocks = 2/CU, LDS 73.5 KB.
// ---------------------------------------------------------------------------
__launch_bounds__(512, 4)
__global__ void conv_kernel(const float* __restrict__ x,
                            const uint4* __restrict__ tabs,
                            float* __restrict__ s0out,
                            float* __restrict__ s1out) {
    __shared__ _Float16 gray[96 * GS];       // 19968 B
    __shared__ _Float16 Tre[2][64 * GS];     // 2 x 13312 B  (T^T: [col c][row m])
    __shared__ _Float16 Tim[2][64 * GS];     // 2 x 13312 B
    __shared__ float    s1st[NFILT * 16];    // 2048 B, staged pooled outputs

    const int bx = blockIdx.x;
    const int n  = bx >> 6;                  // image
    const int t6 = bx & 63;                  // tile
    const int ty = t6 >> 3, tx = t6 & 7;
    const int r0g = ty * 64 - 16;
    const int c0g = tx * 64 - 16;            // 16-aligned -> float4-aligned
    const int tid = threadIdx.x;

    // ---- stage gray = 3-channel mean (f16), float4 loads, group bounds ----
    {
        const float* c0p = x + (size_t)n * 3 * IMG * IMG;
        const float* c1p = c0p + IMG * IMG;
        const float* c2p = c0p + 2 * IMG * IMG;
        for (int e = tid; e < 96 * 24; e += 512) {
            int hr = e / 24, g4 = e - hr * 24;
            int hc0 = g4 * 4;
            int gr = r0g + hr, gc0 = c0g + hc0;
            float4 v = make_float4(0.f, 0.f, 0.f, 0.f);
            if (hr < 95 && (unsigned)gr < IMG && (unsigned)gc0 < IMG) {
                size_t off = ((size_t)gr * IMG + gc0) >> 2;
                float4 a = ((const float4*)c0p)[off];
                float4 b = ((const float4*)c1p)[off];
                float4 c = ((const float4*)c2p)[off];
                v.x = (a.x + b.x + c.x) * (1.0f / 3.0f);
                v.y = (a.y + b.y + c.y) * (1.0f / 3.0f);
                v.z = (a.z + b.z + c.z) * (1.0f / 3.0f);
                v.w = (hc0 == 92) ? 0.0f : (a.w + b.w + c.w) * (1.0f / 3.0f);
            }
            uint2 w2;
            w2.x = pkrtz(v.x, v.y);
            w2.y = pkrtz(v.z, v.w);
            *(uint2*)(&gray[hr * GS + hc0]) = w2;
        }
    }
    __syncthreads();

    // ---- fused S0: 16x16 avg-pool of gray interior ----
    if (tid < 256) {
        int cell = tid >> 4, sub = tid & 15;
        int pr = cell >> 2, pc = cell & 3;
        const _Float16* row = &gray[(16 + pr * 16 + sub) * GS + 16 + pc * 16];
        float s = 0.0f;
        #pragma unroll
        for (int j = 0; j < 16; ++j) s += (float)row[j];
        s += __shfl_xor(s, 1);
        s += __shfl_xor(s, 2);
        s += __shfl_xor(s, 4);
        s += __shfl_xor(s, 8);
        if (sub == 0)
            s0out[(size_t)n * 1024 + (ty * 4 + pr) * 32 + (tx * 4 + pc)] = s * (1.0f / 256.0f);
    }

    const int lane = tid & 63;
    const int w    = tid >> 6;
    const int r4   = w & 3;                 // pass A N-tile / pass B M-tile
    const int half = w >> 2;                // splits mt (pass A) / nt (pass B)
    const int nn   = lane & 15;
    const int q8   = (lane >> 4) << 3;      // k-offset within K=32 fragment
    const int q4   = (lane >> 4) << 2;      // C/D row base within 16-tile
    const int cr   = r4 * 16 + nn;          // pass A: col c; pass B: row r
    const int u    = q8 - cr + 64;          // tap-phase for fragment tables
    const int b0   = r4 >> 1;               // first needed k-block (band skip)
    const int uoff = (u & 7) * 20 + (u >> 3);

    // pair p -> representative filter fa (o=0..3); partner fb = conj
    // fa = (p>>2)*8 + (p&3),  fb = (p>>2)*8 + 7 - (p&3)

    // ---- hoist filter-invariant gray A-fragments into registers ----
    v8h Agray[3][2];
    #pragma unroll
    for (int mi = 0; mi < 3; ++mi)
        #pragma unroll
        for (int j = 0; j < 2; ++j)
            Agray[mi][j] = *(const v8h*)(&gray[((half * 3 + mi) * 16 + nn) * GS + (b0 + j) * 32 + q8]);

    // ---- prologue: A(pair 0) -> T[0]; F(0) loads issued before barrier ----
    v8h Fre[2], Fim[2];
    {
        const uint4* fb0 = tabs + uoff;     // fa(0) = filter 0
        v8h Gre0[2], Gim0[2];
        #pragma unroll
        for (int j = 0; j < 2; ++j) {
            int idx = (b0 + j) * 4;
            Gre0[j] = ldfrag(fb0 + idx);
            Gim0[j] = ldfrag(fb0 + 160 + idx);
        }
        #pragma unroll
        for (int mi = 0; mi < 3; ++mi) {
            int mt = half * 3 + mi;
            v4f aR = {0.f, 0.f, 0.f, 0.f}, aI = {0.f, 0.f, 0.f, 0.f};
            #pragma unroll
            for (int j = 0; j < 2; ++j) {
                aR = __builtin_amdgcn_mfma_f32_16x16x32_f16(Agray[mi][j], Gre0[j], aR, 0, 0, 0);
                aI = __builtin_amdgcn_mfma_f32_16x16x32_f16(Agray[mi][j], Gim0[j], aI, 0, 0, 0);
            }
            int mb = mt * 16 + q4;
            uint2 pr, pi;
            pr.x = pkrtz(aR[0], aR[1]);  pr.y = pkrtz(aR[2], aR[3]);
            pi.x = pkrtz(aI[0], aI[1]);  pi.y = pkrtz(aI[2], aI[3]);
            *(uint2*)(&Tre[0][cr * GS + mb]) = pr;
            *(uint2*)(&Tim[0][cr * GS + mb]) = pi;
        }
        #pragma unroll
        for (int j = 0; j < 2; ++j) {
            int idx = (b0 + j) * 4;
            Fre[j] = ldfrag(fb0 + 320 + idx);
            Fim[j] = ldfrag(fb0 + 480 + idx);
        }
    }
    __syncthreads();

    // ---- main loop over 16 conjugate pairs, one barrier each ----
    for (int p = 0; p < NPAIR; ++p) {
        const _Float16* Tr  = Tre[p & 1];
        const _Float16* Ti  = Tim[p & 1];
        _Float16*       Trn = Tre[(p + 1) & 1];
        _Float16*       Tin = Tim[(p + 1) & 1];
        const int fa  = ((p >> 2) << 3) + (p & 3);
        const int fbi = ((p >> 2) << 3) + 7 - (p & 3);
        const int nxp = (p < NPAIR - 1) ? p + 1 : p;
        const int nxfa = ((nxp >> 2) << 3) + (nxp & 3);
        const uint4* fbn = tabs + (size_t)nxfa * 800 + uoff;

        // ---- G(p+1) prefetch: issued early, consumed after pass B ----
        v8h Gre[2], Gim[2];
        #pragma unroll
        for (int j = 0; j < 2; ++j) {
            int idx = (b0 + j) * 4;
            Gre[j] = ldfrag(fbn + idx);
            Gim[j] = ldfrag(fbn + 160 + idx);
        }

        // ---- pass B: P1..P4 chains give BOTH filters of the pair ----
        #pragma unroll
        for (int ni = 0; ni < 2; ++ni) {
            int nt = half * 2 + ni;
            v4f P1 = {0.f, 0.f, 0.f, 0.f}, P2 = {0.f, 0.f, 0.f, 0.f};
            v4f P3 = {0.f, 0.f, 0.f, 0.f}, P4 = {0.f, 0.f, 0.f, 0.f};
            #pragma unroll
            for (int j = 0; j < 2; ++j) {
                v8h tR = *(const v8h*)(&Tr[(nt * 16 + nn) * GS + (b0 + j) * 32 + q8]);
                v8h tI = *(const v8h*)(&Ti[(nt * 16 + nn) * GS + (b0 + j) * 32 + q8]);
                P1 = __builtin_amdgcn_mfma_f32_16x16x32_f16(Fre[j], tR, P1, 0, 0, 0);
                P2 = __builtin_amdgcn_mfma_f32_16x16x32_f16(Fim[j], tI, P2, 0, 0, 0);
                P3 = __builtin_amdgcn_mfma_f32_16x16x32_f16(Fre[j], tI, P3, 0, 0, 0);
                P4 = __builtin_amdgcn_mfma_f32_16x16x32_f16(Fim[j], tR, P4, 0, 0, 0);
            }
            // magnitudes for fa = (P1-P2, P3+P4) and fb = (P1+P2, P3-P4)
            float ma = 0.0f, mb = 0.0f;
            #pragma unroll
            for (int r = 0; r < 4; ++r) {
                float are = P1[r] - P2[r], aim = P3[r] + P4[r];
                float bre = P1[r] + P2[r], bim = P3[r] - P4[r];
                ma += fsqrt(fmaf(are, are, fmaf(aim, aim, 1e-8f)));
                mb += fsqrt(fmaf(bre, bre, fmaf(bim, bim, 1e-8f)));
            }
            ma = dpp_add<0xB1>(ma);   mb = dpp_add<0xB1>(mb);   // quad_perm xor1
            ma = dpp_add<0x4E>(ma);   mb = dpp_add<0x4E>(mb);   // quad_perm xor2
            ma = dpp_add<0x141>(ma);  mb = dpp_add<0x141>(mb);  // row_half_mirror
            ma = dpp_add<0x140>(ma);  mb = dpp_add<0x140>(mb);  // row_mirror
            ma += __shfl_xor(ma, 16); mb += __shfl_xor(mb, 16);
            ma += __shfl_xor(ma, 32); mb += __shfl_xor(mb, 32);
            if (lane == 0) {
                s1st[fa  * 16 + r4 * 4 + nt] = ma;
                s1st[fbi * 16 + r4 * 4 + nt] = mb;
            }
        }

        // ---- pass A(p+1): gray . G -> T[(p+1)&1]; then F(p+1) loads ----
        if (p < NPAIR - 1) {
            #pragma unroll
            for (int mi = 0; mi < 3; ++mi) {
                int mt = half * 3 + mi;
                v4f aR = {0.f, 0.f, 0.f, 0.f}, aI = {0.f, 0.f, 0.f, 0.f};
                #pragma unroll
                for (int j = 0; j < 2; ++j) {
                    aR = __builtin_amdgcn_mfma_f32_16x16x32_f16(Agray[mi][j], Gre[j], aR, 0, 0, 0);
                    aI = __builtin_amdgcn_mfma_f32_16x16x32_f16(Agray[mi][j], Gim[j], aI, 0, 0, 0);
                }
                int mb = mt * 16 + q4;
                uint2 pr, pi;
                pr.x = pkrtz(aR[0], aR[1]);  pr.y = pkrtz(aR[2], aR[3]);
                pi.x = pkrtz(aI[0], aI[1]);  pi.y = pkrtz(aI[2], aI[3]);
                *(uint2*)(&Trn[cr * GS + mb]) = pr;
                *(uint2*)(&Tin[cr * GS + mb]) = pi;
            }
            // F(p+1) prefetch: latency spans the barrier into next iteration
            #pragma unroll
            for (int j = 0; j < 2; ++j) {
                int idx = (b0 + j) * 4;
                Fre[j] = ldfrag(fbn + 320 + idx);
                Fim[j] = ldfrag(fbn + 480 + idx);
            }
        }
        __syncthreads();        // T[(p+1)&1] ready; T[p&1] free
    }

    // ---- epilogue: flush staged S1 (loop ended with a barrier) ----
    float* s1b = s1out + (size_t)n * NFILT * 32 * 32;
    for (int e = tid; e < NFILT * 16; e += 512) {
        int fi = e >> 4, cell = e & 15;
        int r4c = cell >> 2, ntc = cell & 3;
        s1b[((size_t)fi * 32 + (ty * 4 + r4c)) * 32 + (tx * 4 + ntc)] =
            s1st[e] * (1.0f / 256.0f);
    }
}

// ---------------------------------------------------------------------------
extern "C" void kernel_launch(void* const* d_in, const int* in_sizes, int n_in,
                              void* d_out, int out_size, void* d_ws, size_t ws_size,
                              hipStream_t stream) {
    const float* x = (const float*)d_in[0];
    float* out = (float*)d_out;
    unsigned* tabs = (unsigned*)d_ws;          // 102400 dwords = 400 KB scratch

    hipLaunchKernelGGL(make_tables, dim3(32), dim3(256), 0, stream, tabs);
    hipLaunchKernelGGL(conv_kernel, dim3(512), dim3(512), 0, stream,
                       x, (const uint4*)tabs, out, out + 8192);
}

// Round 3
// 113.298 us; speedup vs baseline: 1.5532x; 1.0077x over previous
//
#include <hip/hip_runtime.h>
#include <math.h>

#define IMG   512
#define NFILT 32
#define NPAIR 16
#define PI_F  3.14159265358979323846f
#define GS    104      // LDS row stride in halves (208 B)

typedef _Float16 v8h __attribute__((ext_vector_type(8)));
typedef float    v4f __attribute__((ext_vector_type(4)));

__device__ __forceinline__ unsigned pkrtz(float a, float b) {
    typedef __fp16 f16x2 __attribute__((ext_vector_type(2)));
    union { f16x2 h; unsigned u; } x;
    x.h = __builtin_amdgcn_cvt_pkrtz(a, b);
    return x.u;
}

template <int CTRL>
__device__ __forceinline__ float dpp_add(float v) {
    int t = __builtin_amdgcn_update_dpp(0, __float_as_int(v), CTRL, 0xf, 0xf, true);
    return v + __int_as_float(t);
}

// lane[i] + lane[i^32] for all lanes, pure VALU (no LDS pipe): gfx950
// v_permlane32_swap_b32 exchanges dst[32:63] <-> src[0:31].
__device__ __forceinline__ float xor32_add(float m) {
    float a = m, b = m;
    asm("v_permlane32_swap_b32 %0, %1" : "+v"(a), "+v"(b));
    return a + b;
}

#if __has_builtin(__builtin_amdgcn_sqrtf)
__device__ __forceinline__ float fsqrt(float x) { return __builtin_amdgcn_sqrtf(x); }
#else
__device__ __forceinline__ float fsqrt(float x) { return sqrtf(x); }
#endif

// Loop barrier: only LDS (T ds_writes) must drain; the G/F global prefetch
// loads stay IN FLIGHT across the barrier (default __syncthreads drains
// vmcnt(0) too, putting table-load latency in the barrier critical path).
__device__ __forceinline__ void bar_lgkm() {
    asm volatile("s_waitcnt lgkmcnt(0)\n\ts_barrier" ::: "memory");
}

__device__ __forceinline__ v8h ldfrag(const uint4* p) {
    union { uint4 u; v8h h; } x; x.u = *p; return x.h;
}

// ---------------------------------------------------------------------------
// tabs layout (dwords): [filter:32][table:5][copy:8][block:20][dw:4]
//   tables: 0 g_re, 1 g_im, 2 f_re, 3 f_im, 4 -f_im (tbl4 kept for layout)
//   copy c, block i holds halves tap(8*i-64+c .. +7); tap(t)=0 unless 0<=t<32.
// ---------------------------------------------------------------------------
__global__ void make_tables(unsigned* __restrict__ tabs) {
    __shared__ _Float16 P[5][168];      // P[tbl][p] = tap(p-64), zero-padded
    const int fo = blockIdx.x;
    const int tid = threadIdx.x;
    for (int e = tid; e < 5 * 168; e += 256) ((_Float16*)P)[e] = (_Float16)0.0f;
    __syncthreads();
    if (tid < 160) {
        int tbl = tid >> 5, t = tid & 31;
        int s = (fo >> 3) + 1, o = fo & 7;
        float theta = (float)o * (PI_F / 7.0f);      // linspace(0, pi, 8)
        float sf = (float)s * 2.0f;                  // scale * SIGMA
        float kf = 2.0f * PI_F / ((float)s * sf);
        float a = kf * cosf(theta), b = kf * sinf(theta);
        float d = (float)(t - 16);
        float env = expf(-0.5f * d * d / (sf * sf));
        float v;
        switch (tbl) {
            case 0: v =  env * cosf(b * d); break;
            case 1: v =  env * sinf(b * d); break;
            case 2: v =  env * cosf(a * d); break;
            case 3: v =  env * sinf(a * d); break;
            default: v = -env * sinf(a * d); break;
        }
        P[tbl][t + 64] = (_Float16)v;
    }
    __syncthreads();
    unsigned* dst = tabs + (size_t)fo * 3200;
    for (int e = tid; e < 3200; e += 256) {
        int tbl  = e / 640;  int rem2 = e - tbl * 640;
        int copy = rem2 / 80; int idw = rem2 - copy * 80;
        int p0 = (idw >> 2) * 8 + copy + (idw & 3) * 2;   // = t0 + 64
        union { unsigned u; _Float16 h[2]; } p;
        p.h[0] = P[tbl][p0];
        p.h[1] = P[tbl][p0 + 1];
        dst[e] = p.u;
    }
}

// ---------------------------------------------------------------------------
// Fused kernel: S0 pool + MFMA separable Gabor conv + |.| + pool -> S1.
// R16: serialization cuts on the R15 conjugate-pair structure.
//   - loop barrier = lgkmcnt(0)+s_barrier only (G/F prefetch spans barrier)
//   - xor-32 reduce via v_permlane32_swap (VALU) instead of ds_bpermute
//   - P-combines as v4f vector ops (v_pk_add_f32), sqrt sum as balanced tree
//   - filter-0 table loads issued before gray staging (latency overlap)
// 512 blocks = 2/CU, LDS 73.5 KB, 16 pair-iterations, one barrier each.
// ---------------------------------------------------------------------------
__launch_bounds__(512, 4)
__global__ void conv_kernel(const float* __restrict__ x,
                            const uint4* __restrict__ tabs,
                            float* __restrict__ s0out,
                            float* __restrict__ s1out) {
    __shared__ _Float16 gray[96 * GS];       // 19968 B
    __shared__ _Float16 Tre[2][64 * GS];     // 2 x 13312 B  (T^T: [col c][row m])
    __shared__ _Float16 Tim[2][64 * GS];     // 2 x 13312 B
    __shared__ float    s1st[NFILT * 16];    // 2048 B, staged pooled outputs

    const int bx = blockIdx.x;
    const int n  = bx >> 6;                  // image
    const int t6 = bx & 63;                  // tile
    const int ty = t6 >> 3, tx = t6 & 7;
    const int r0g = ty * 64 - 16;
    const int c0g = tx * 64 - 16;            // 16-aligned -> float4-aligned
    const int tid = threadIdx.x;

    const int lane = tid & 63;
    const int w    = tid >> 6;
    const int r4   = w & 3;                 // pass A N-tile / pass B M-tile
    const int half = w >> 2;                // splits mt (pass A) / nt (pass B)
    const int nn   = lane & 15;
    const int q8   = (lane >> 4) << 3;      // k-offset within K=32 fragment
    const int q4   = (lane >> 4) << 2;      // C/D row base within 16-tile
    const int cr   = r4 * 16 + nn;          // pass A: col c; pass B: row r
    const int u    = q8 - cr + 64;          // tap-phase for fragment tables
    const int b0   = r4 >> 1;               // first needed k-block (band skip)
    const int uoff = (u & 7) * 20 + (u >> 3);

    // ---- filter-0 G/F loads issued first: latency hides under staging ----
    const uint4* fb0 = tabs + uoff;
    v8h Gre0[2], Gim0[2], Fre[2], Fim[2];
    #pragma unroll
    for (int j = 0; j < 2; ++j) {
        int idx = (b0 + j) * 4;
        Gre0[j] = ldfrag(fb0 + idx);
        Gim0[j] = ldfrag(fb0 + 160 + idx);
        Fre[j]  = ldfrag(fb0 + 320 + idx);
        Fim[j]  = ldfrag(fb0 + 480 + idx);
    }

    // ---- stage gray = 3-channel mean (f16), float4 loads, group bounds ----
    {
        const float* c0p = x + (size_t)n * 3 * IMG * IMG;
        const float* c1p = c0p + IMG * IMG;
        const float* c2p = c0p + 2 * IMG * IMG;
        for (int e = tid; e < 96 * 24; e += 512) {
            int hr = e / 24, g4 = e - hr * 24;
            int hc0 = g4 * 4;
            int gr = r0g + hr, gc0 = c0g + hc0;
            float4 v = make_float4(0.f, 0.f, 0.f, 0.f);
            if (hr < 95 && (unsigned)gr < IMG && (unsigned)gc0 < IMG) {
                size_t off = ((size_t)gr * IMG + gc0) >> 2;
                float4 a = ((const float4*)c0p)[off];
                float4 b = ((const float4*)c1p)[off];
                float4 c = ((const float4*)c2p)[off];
                v.x = (a.x + b.x + c.x) * (1.0f / 3.0f);
                v.y = (a.y + b.y + c.y) * (1.0f / 3.0f);
                v.z = (a.z + b.z + c.z) * (1.0f / 3.0f);
                v.w = (hc0 == 92) ? 0.0f : (a.w + b.w + c.w) * (1.0f / 3.0f);
            }
            uint2 w2;
            w2.x = pkrtz(v.x, v.y);
            w2.y = pkrtz(v.z, v.w);
            *(uint2*)(&gray[hr * GS + hc0]) = w2;
        }
    }
    __syncthreads();

    // ---- fused S0: 16x16 avg-pool of gray interior ----
    if (tid < 256) {
        int cell = tid >> 4, sub = tid & 15;
        int pr = cell >> 2, pc = cell & 3;
        const _Float16* row = &gray[(16 + pr * 16 + sub) * GS + 16 + pc * 16];
        float s = 0.0f;
        #pragma unroll
        for (int j = 0; j < 16; ++j) s += (float)row[j];
        s += __shfl_xor(s, 1);
        s += __shfl_xor(s, 2);
        s += __shfl_xor(s, 4);
        s += __shfl_xor(s, 8);
        if (sub == 0)
            s0out[(size_t)n * 1024 + (ty * 4 + pr) * 32 + (tx * 4 + pc)] = s * (1.0f / 256.0f);
    }

    // pair p -> representative filter fa (o=0..3); partner fb = conj
    // fa = (p>>2)*8 + (p&3),  fb = (p>>2)*8 + 7 - (p&3)

    // ---- hoist filter-invariant gray A-fragments into registers ----
    v8h Agray[3][2];
    #pragma unroll
    for (int mi = 0; mi < 3; ++mi)
        #pragma unroll
        for (int j = 0; j < 2; ++j)
            Agray[mi][j] = *(const v8h*)(&gray[((half * 3 + mi) * 16 + nn) * GS + (b0 + j) * 32 + q8]);

    // ---- prologue: A(pair 0) -> T[0] ----
    #pragma unroll
    for (int mi = 0; mi < 3; ++mi) {
        int mt = half * 3 + mi;
        v4f aR = {0.f, 0.f, 0.f, 0.f}, aI = {0.f, 0.f, 0.f, 0.f};
        #pragma unroll
        for (int j = 0; j < 2; ++j) {
            aR = __builtin_amdgcn_mfma_f32_16x16x32_f16(Agray[mi][j], Gre0[j], aR, 0, 0, 0);
            aI = __builtin_amdgcn_mfma_f32_16x16x32_f16(Agray[mi][j], Gim0[j], aI, 0, 0, 0);
        }
        int mb = mt * 16 + q4;
        uint2 pr, pi;
        pr.x = pkrtz(aR[0], aR[1]);  pr.y = pkrtz(aR[2], aR[3]);
        pi.x = pkrtz(aI[0], aI[1]);  pi.y = pkrtz(aI[2], aI[3]);
        *(uint2*)(&Tre[0][cr * GS + mb]) = pr;
        *(uint2*)(&Tim[0][cr * GS + mb]) = pi;
    }
    __syncthreads();

    // ---- main loop over 16 conjugate pairs, one lgkm-barrier each ----
    for (int p = 0; p < NPAIR; ++p) {
        const _Float16* Tr  = Tre[p & 1];
        const _Float16* Ti  = Tim[p & 1];
        _Float16*       Trn = Tre[(p + 1) & 1];
        _Float16*       Tin = Tim[(p + 1) & 1];
        const int fa  = ((p >> 2) << 3) + (p & 3);
        const int fbi = ((p >> 2) << 3) + 7 - (p & 3);
        const int nxp = (p < NPAIR - 1) ? p + 1 : p;
        const int nxfa = ((nxp >> 2) << 3) + (nxp & 3);
        const uint4* fbn = tabs + (size_t)nxfa * 800 + uoff;

        // ---- G(p+1) prefetch: issued early, consumed after pass B ----
        v8h Gre[2], Gim[2];
        #pragma unroll
        for (int j = 0; j < 2; ++j) {
            int idx = (b0 + j) * 4;
            Gre[j] = ldfrag(fbn + idx);
            Gim[j] = ldfrag(fbn + 160 + idx);
        }

        // ---- pass B: P1..P4 chains give BOTH filters of the pair ----
        #pragma unroll
        for (int ni = 0; ni < 2; ++ni) {
            int nt = half * 2 + ni;
            v4f P1 = {0.f, 0.f, 0.f, 0.f}, P2 = {0.f, 0.f, 0.f, 0.f};
            v4f P3 = {0.f, 0.f, 0.f, 0.f}, P4 = {0.f, 0.f, 0.f, 0.f};
            #pragma unroll
            for (int j = 0; j < 2; ++j) {
                v8h tR = *(const v8h*)(&Tr[(nt * 16 + nn) * GS + (b0 + j) * 32 + q8]);
                v8h tI = *(const v8h*)(&Ti[(nt * 16 + nn) * GS + (b0 + j) * 32 + q8]);
                P1 = __builtin_amdgcn_mfma_f32_16x16x32_f16(Fre[j], tR, P1, 0, 0, 0);
                P2 = __builtin_amdgcn_mfma_f32_16x16x32_f16(Fim[j], tI, P2, 0, 0, 0);
                P3 = __builtin_amdgcn_mfma_f32_16x16x32_f16(Fre[j], tI, P3, 0, 0, 0);
                P4 = __builtin_amdgcn_mfma_f32_16x16x32_f16(Fim[j], tR, P4, 0, 0, 0);
            }
            // fa = (P1-P2, P3+P4), fb = (P1+P2, P3-P4): vector combines
            // (v_pk_add_f32-able), then independent sqrts summed as a tree.
            v4f are = P1 - P2, aim = P3 + P4;
            v4f bre = P1 + P2, bim = P3 - P4;
            float sa0 = fsqrt(fmaf(are[0], are[0], fmaf(aim[0], aim[0], 1e-8f)));
            float sa1 = fsqrt(fmaf(are[1], are[1], fmaf(aim[1], aim[1], 1e-8f)));
            float sa2 = fsqrt(fmaf(are[2], are[2], fmaf(aim[2], aim[2], 1e-8f)));
            float sa3 = fsqrt(fmaf(are[3], are[3], fmaf(aim[3], aim[3], 1e-8f)));
            float sb0 = fsqrt(fmaf(bre[0], bre[0], fmaf(bim[0], bim[0], 1e-8f)));
            float sb1 = fsqrt(fmaf(bre[1], bre[1], fmaf(bim[1], bim[1], 1e-8f)));
            float sb2 = fsqrt(fmaf(bre[2], bre[2], fmaf(bim[2], bim[2], 1e-8f)));
            float sb3 = fsqrt(fmaf(bre[3], bre[3], fmaf(bim[3], bim[3], 1e-8f)));
            float ma = (sa0 + sa1) + (sa2 + sa3);
            float mb = (sb0 + sb1) + (sb2 + sb3);
            ma = dpp_add<0xB1>(ma);   mb = dpp_add<0xB1>(mb);   // quad_perm xor1
            ma = dpp_add<0x4E>(ma);   mb = dpp_add<0x4E>(mb);   // quad_perm xor2
            ma = dpp_add<0x141>(ma);  mb = dpp_add<0x141>(mb);  // row_half_mirror
            ma = dpp_add<0x140>(ma);  mb = dpp_add<0x140>(mb);  // row_mirror
            ma += __shfl_xor(ma, 16); mb += __shfl_xor(mb, 16);
            ma = xor32_add(ma);       mb = xor32_add(mb);       // VALU, no LDS
            if (lane == 0) {
                s1st[fa  * 16 + r4 * 4 + nt] = ma;
                s1st[fbi * 16 + r4 * 4 + nt] = mb;
            }
        }

        // ---- pass A(p+1): gray . G -> T[(p+1)&1]; then F(p+1) loads ----
        if (p < NPAIR - 1) {
            #pragma unroll
            for (int mi = 0; mi < 3; ++mi) {
                int mt = half * 3 + mi;
                v4f aR = {0.f, 0.f, 0.f, 0.f}, aI = {0.f, 0.f, 0.f, 0.f};
                #pragma unroll
                for (int j = 0; j < 2; ++j) {
                    aR = __builtin_amdgcn_mfma_f32_16x16x32_f16(Agray[mi][j], Gre[j], aR, 0, 0, 0);
                    aI = __builtin_amdgcn_mfma_f32_16x16x32_f16(Agray[mi][j], Gim[j], aI, 0, 0, 0);
                }
                int mb = mt * 16 + q4;
                uint2 pr, pi;
                pr.x = pkrtz(aR[0], aR[1]);  pr.y = pkrtz(aR[2], aR[3]);
                pi.x = pkrtz(aI[0], aI[1]);  pi.y = pkrtz(aI[2], aI[3]);
                *(uint2*)(&Trn[cr * GS + mb]) = pr;
                *(uint2*)(&Tin[cr * GS + mb]) = pi;
            }
            // F(p+1) prefetch: latency spans the lgkm-barrier (stays in flight)
            #pragma unroll
            for (int j = 0; j < 2; ++j) {
                int idx = (b0 + j) * 4;
                Fre[j] = ldfrag(fbn + 320 + idx);
                Fim[j] = ldfrag(fbn + 480 + idx);
            }
        }
        bar_lgkm();             // T ds_writes drained; global loads in flight
    }

    // ---- epilogue: flush staged S1 (loop ended with a barrier) ----
    float* s1b = s1out + (size_t)n * NFILT * 32 * 32;
    for (int e = tid; e < NFILT * 16; e += 512) {
        int fi = e >> 4, cell = e & 15;
        int r4c = cell >> 2, ntc = cell & 3;
        s1b[((size_t)fi * 32 + (ty * 4 + r4c)) * 32 + (tx * 4 + ntc)] =
            s1st[e] * (1.0f / 256.0f);
    }
}

// ---------------------------------------------------------------------------
extern "C" void kernel_launch(void* const* d_in, const int* in_sizes, int n_in,
                              void* d_out, int out_size, void* d_ws, size_t ws_size,
                              hipStream_t stream) {
    const float* x = (const float*)d_in[0];
    float* out = (float*)d_out;
    unsigned* tabs = (unsigned*)d_ws;          // 102400 dwords = 400 KB scratch

    hipLaunchKernelGGL(make_tables, dim3(32), dim3(256), 0, stream, tabs);
    hipLaunchKernelGGL(conv_kernel, dim3(512), dim3(512), 0, stream,
                       x, (const uint4*)tabs, out, out + 8192);
}